// Round 5
// baseline (453.431 us; speedup 1.0000x reference)
//
#include <hip/hip_runtime.h>
#include <hip/hip_bf16.h>

// MoE SwiGLU MLP, sparse top-2 path.
// T=2048 tokens, D_MODEL=1024, D_FF=2048, E=8 experts, K=2.
// R5 383.7us. R6: prep pattern rewrite = null (2.2 TB/s invariant).
// R8 349.0us: router+WgWu-prep fused; gu+Wd-prep fused. gu showed MfmaUtil 15.7%,
//     VALU 16.5%, HBM 31% — latency-bound, 5x above its 16us MFMA floor.
// R9: KILL the prep stage. GEMMs read fp32 weights directly; B-staging does the
//     R4-verified 8k x 4n register transpose + RTNE cvt, writing the SAME
//     k-inner-8 bf16 LDS image (MFMA loops untouched). No global_load_lds left
//     => __syncthreads drains lgkm only => cross-barrier reg prefetch (T14)
//     pipelines next-kt loads under MFMA. Weight re-reads are L3-served.
//     Removes ~85-90us of prep + 100MB Wd round-trip.
//     Predict total 349 -> 200-260us; gu 50-75us @ MfmaUtil 20-35%.

#define D_MODEL 1024
#define D_FF    2048
#define N_EXP   8
#define T_TOK   2048
#define MAXTILES 40   // sum_e ceil(cnt_e/128) <= 32+7 < 40

typedef __attribute__((ext_vector_type(8))) short bf16x8;
typedef __attribute__((ext_vector_type(8))) ushort u16x8;
typedef __attribute__((ext_vector_type(4))) float f32x4;

__device__ __forceinline__ ushort f2bf(float f) {
    union { float f; unsigned u; } c; c.f = f;
    unsigned u = c.u;
    return (ushort)((u + 0x7fffu + ((u >> 16) & 1u)) >> 16);  // RTNE
}

// ---------------- router: 64 blocks x 32 tokens, block-aggregated atomics ----------------
// Also emits xb (bf16 copy of x) since it reads every x element anyway.
__global__ __launch_bounds__(256) void k_router(
    const float* __restrict__ x, const float* __restrict__ gw, const float* __restrict__ gb,
    int* cnt, float* probsum, int* tok, int* slotpk, float* wtok,
    ushort* __restrict__ xb)
{
    __shared__ float gws[N_EXP * D_MODEL];   // 32 KB
    __shared__ float ps_s[N_EXP];
    __shared__ int   bc_s[N_EXP];
    __shared__ int   gb_s[N_EXP];
    __shared__ int   a_e[64];                // 32 tokens x 2 assignments
    __shared__ int   a_lp[64];

    int tid = threadIdx.x;
    for (int i = tid; i < N_EXP * D_MODEL / 4; i += 256)
        ((float4*)gws)[i] = ((const float4*)gw)[i];
    if (tid < N_EXP) { ps_s[tid] = 0.f; bc_s[tid] = 0; }
    __syncthreads();

    int wave = tid >> 6, lane = tid & 63;

    for (int it = 0; it < 8; it++) {
        int tb = it * 4 + wave;                      // token-in-block
        int t = blockIdx.x * 32 + tb;
        const float4* xr = (const float4*)(x + (size_t)t * D_MODEL);
        ushort* xbr = xb + (size_t)t * D_MODEL;

        float acc[N_EXP];
#pragma unroll
        for (int e = 0; e < N_EXP; e++) acc[e] = 0.f;
#pragma unroll
        for (int q = 0; q < 4; q++) {
            int idx = q * 64 + lane;                 // coalesced + uniform banking
            float4 xv = xr[idx];
            ushort4 xc;
            xc.x = f2bf(xv.x); xc.y = f2bf(xv.y); xc.z = f2bf(xv.z); xc.w = f2bf(xv.w);
            *(ushort4*)&xbr[idx * 4] = xc;
#pragma unroll
            for (int e = 0; e < N_EXP; e++) {
                float4 gv = ((const float4*)(gws + e * D_MODEL))[idx];
                acc[e] += xv.x * gv.x + xv.y * gv.y + xv.z * gv.z + xv.w * gv.w;
            }
        }
#pragma unroll
        for (int off = 32; off > 0; off >>= 1) {
#pragma unroll
            for (int e = 0; e < N_EXP; e++) acc[e] += __shfl_xor(acc[e], off, 64);
        }
        if (lane == 0) {
            float l[N_EXP], m = -1e30f;
#pragma unroll
            for (int e = 0; e < N_EXP; e++) { l[e] = acc[e] + gb[e]; m = fmaxf(m, l[e]); }
            float p[N_EXP], s = 0.f;
#pragma unroll
            for (int e = 0; e < N_EXP; e++) { p[e] = expf(l[e] - m); s += p[e]; }
            float inv = 1.f / s;
#pragma unroll
            for (int e = 0; e < N_EXP; e++) { p[e] *= inv; atomicAdd(&ps_s[e], p[e]); }
            // top-2, lowest index wins ties (matches lax.top_k)
            int i0 = 0; float v0 = p[0];
#pragma unroll
            for (int e = 1; e < N_EXP; e++) if (p[e] > v0) { v0 = p[e]; i0 = e; }
            int i1 = -1; float v1 = -1.f;
#pragma unroll
            for (int e = 0; e < N_EXP; e++) if (e != i0 && p[e] > v1) { v1 = p[e]; i1 = e; }
            float winv = 1.f / (v0 + v1);
            int lp0 = atomicAdd(&bc_s[i0], 1);
            int lp1 = atomicAdd(&bc_s[i1], 1);
            a_e[tb * 2 + 0] = i0; a_lp[tb * 2 + 0] = lp0;
            a_e[tb * 2 + 1] = i1; a_lp[tb * 2 + 1] = lp1;
            wtok[t * 2 + 0] = v0 * winv;
            wtok[t * 2 + 1] = v1 * winv;
        }
    }
    __syncthreads();
    if (tid < N_EXP) {
        gb_s[tid] = atomicAdd(&cnt[tid], bc_s[tid]);
        atomicAdd(&probsum[tid], ps_s[tid]);
    }
    __syncthreads();
    if (tid < 64) {
        int tb = tid >> 1, k = tid & 1;
        int t = blockIdx.x * 32 + tb;
        int e = a_e[tid];
        int slot = gb_s[e] + a_lp[tid];
        tok[e * T_TOK + slot] = t;
        slotpk[t * 2 + k] = (e << 16) | slot;
    }
}

// ---------------- 128-aligned expert bases + tile table + balance loss ----------------
__global__ void k_base_loss(const int* __restrict__ cnt, const float* __restrict__ probsum,
                            int* abase, int* tile, float* loss_out)
{
    if (threadIdx.x == 0 && blockIdx.x == 0) {
        int b = 0, nt = 0;
        float loss = 0.f;
        for (int e = 0; e < N_EXP; e++) {
            abase[e] = b;
            for (int m0 = 0; m0 < cnt[e]; m0 += 128)
                tile[nt++] = (e << 16) | m0;
            b += ((cnt[e] + 127) >> 7) * 128;           // capacity-aligned
            float mean = probsum[e] * (1.0f / T_TOK);
            loss += 0.125f * (logf(0.125f) - logf(mean + 1e-9f));
        }
        for (; nt < MAXTILES; nt++) tile[nt] = -1;
        *loss_out = loss;
    }
}

// ---------------- stage A: h = silu(x@Wg + bg) * (x@Wu + bu) ----------------
// 128x128 tile, BK=64, 4 waves, dual accumulators. B staged DIRECTLY from fp32
// weights: 8 float4 along k per thread (R4-verified transform), in-reg 8k x 4n
// transpose + RTNE cvt, k-inner-8 bf16 LDS image. Next-kt loads prefetched into
// regs before the compute barrier (no global_load_lds => barrier drains lgkm only).
__global__ __launch_bounds__(256, 2) void k_expert_gu(
    const float* __restrict__ Wg, const float* __restrict__ Wu,
    const float* __restrict__ bg, const float* __restrict__ bu,
    const ushort* __restrict__ xb, const int* __restrict__ cnt,
    const int* __restrict__ abase, const int* __restrict__ tile,
    const int* __restrict__ tok, ushort* __restrict__ h_t)
{
    int ti = tile[blockIdx.x];
    if (ti < 0) return;                       // contiguous tail only
    int e = ti >> 16, m0 = ti & 0xffff;
    int ne = cnt[e];
    int nt = blockIdx.y;                      // 0..15
    int n0 = nt * 128;
    int stile = (abase[e] >> 7) + (m0 >> 7);  // global aligned slot-tile

    __shared__ __align__(16) ushort As[128 * 88];     // stride 88: 16B aligned, 2-way banks
    __shared__ __align__(16) ushort Bg_s[8192];       // k-inner-8 image (16KB)
    __shared__ __align__(16) ushort Bu_s[8192];

    int tid = threadIdx.x;
    int lane = tid & 63, wave = tid >> 6;
    int wm = (wave & 1) * 64, wn = (wave >> 1) * 64;

    // A staging: thread -> (row, k-half)
    int arow = tid >> 1;
    int akh = (tid & 1) * 32;
    int atok = tok[e * T_TOK + min(m0 + arow, ne - 1)];
    const ushort* xrow = xb + (size_t)atok * D_MODEL;

    // B fp32 staging position: thread -> (k-octet skb, 4 cols at sc4)
    int skb = tid >> 5;                  // 0..7
    int sc4 = (tid & 31) * 4;            // 0..124
    const float* gp = Wg + (size_t)e * D_MODEL * D_FF + (size_t)(skb * 8) * D_FF + n0 + sc4;
    const float* up = Wu + (size_t)e * D_MODEL * D_FF + (size_t)(skb * 8) * D_FF + n0 + sc4;
    ushort* dgs = Bg_s + (skb * 128 + sc4) * 8;
    ushort* dus = Bu_s + (skb * 128 + sc4) * 8;

    f32x4 accg[4][4], accu[4][4];
#pragma unroll
    for (int i = 0; i < 4; i++)
#pragma unroll
        for (int j = 0; j < 4; j++) {
            accg[i][j] = (f32x4){0.f, 0.f, 0.f, 0.f};
            accu[i][j] = (f32x4){0.f, 0.f, 0.f, 0.f};
        }

    // preload kt=0 B-subpanels into registers
    float4 vg[8], vu[8];
#pragma unroll
    for (int j = 0; j < 8; j++) {
        vg[j] = *(const float4*)(gp + (size_t)j * D_FF);
        vu[j] = *(const float4*)(up + (size_t)j * D_FF);
    }

    for (int kt = 0; kt < D_MODEL / 64; kt++) {
        __syncthreads();
        // A tile: bf16 gather copy, 16B chunks
#pragma unroll
        for (int q = 0; q < 4; q++)
            *(uint4*)&As[arow * 88 + akh + q * 8] = *(const uint4*)&xrow[kt * 64 + akh + q * 8];
        // B tiles: cvt held regs -> k-inner-8 bf16 LDS
        u16x8 g0, g1, g2, g3, u0, u1, u2, u3;
#pragma unroll
        for (int j = 0; j < 8; j++) {
            g0[j] = f2bf(vg[j].x); g1[j] = f2bf(vg[j].y); g2[j] = f2bf(vg[j].z); g3[j] = f2bf(vg[j].w);
            u0[j] = f2bf(vu[j].x); u1[j] = f2bf(vu[j].y); u2[j] = f2bf(vu[j].z); u3[j] = f2bf(vu[j].w);
        }
        *(u16x8*)(dgs + 0)  = g0; *(u16x8*)(dgs + 8)  = g1;
        *(u16x8*)(dgs + 16) = g2; *(u16x8*)(dgs + 24) = g3;
        *(u16x8*)(dus + 0)  = u0; *(u16x8*)(dus + 8)  = u1;
        *(u16x8*)(dus + 16) = u2; *(u16x8*)(dus + 24) = u3;
        // prefetch next kt's fp32 subpanels (fly during MFMA phase)
        if (kt < D_MODEL / 64 - 1) {
            const float* gn = gp + (size_t)(kt + 1) * 64 * D_FF;
            const float* un = up + (size_t)(kt + 1) * 64 * D_FF;
#pragma unroll
            for (int j = 0; j < 8; j++) {
                vg[j] = *(const float4*)(gn + (size_t)j * D_FF);
                vu[j] = *(const float4*)(un + (size_t)j * D_FF);
            }
        }
        __syncthreads();
        // compute
#pragma unroll
        for (int ks = 0; ks < 2; ks++) {
            bf16x8 af[4];
            int arow_f = wm + (lane & 15);
            int akb = ks * 32 + (lane >> 4) * 8;
#pragma unroll
            for (int sm = 0; sm < 4; sm++)
                af[sm] = *(const bf16x8*)&As[(arow_f + sm * 16) * 88 + akb];
            int bkb = ks * 4 + (lane >> 4);
#pragma unroll
            for (int sn = 0; sn < 4; sn++) {
                int ncol = wn + sn * 16 + (lane & 15);
                bf16x8 bgf = *(const bf16x8*)&Bg_s[(bkb * 128 + ncol) * 8];
                bf16x8 buf = *(const bf16x8*)&Bu_s[(bkb * 128 + ncol) * 8];
#pragma unroll
                for (int sm = 0; sm < 4; sm++) {
                    accg[sm][sn] = __builtin_amdgcn_mfma_f32_16x16x32_bf16(af[sm], bgf, accg[sm][sn], 0, 0, 0);
                    accu[sm][sn] = __builtin_amdgcn_mfma_f32_16x16x32_bf16(af[sm], buf, accu[sm][sn], 0, 0, 0);
                }
            }
        }
    }
    // epilogue: silu(g)*u -> h_t (bf16, tiled k-inner-8 for stage B's A-operand)
    int rbase = wm + ((lane >> 4) << 2);
    int cbase = wn + (lane & 15);
    size_t tbase = (size_t)stile * 32 * 8192;
#pragma unroll
    for (int sm = 0; sm < 4; sm++) {
#pragma unroll
        for (int r = 0; r < 4; r++) {
            int pos = m0 + rbase + sm * 16 + r;
            if (pos < ne) {
                int row = pos & 127;
#pragma unroll
                for (int sn = 0; sn < 4; sn++) {
                    int col = n0 + cbase + sn * 16;
                    float g = accg[sm][sn][r] + bg[e * D_FF + col];
                    float u = accu[sm][sn][r] + bu[e * D_FF + col];
                    float hv = (g / (1.f + expf(-g))) * u;
                    int ktb = col >> 6, kb = (col >> 3) & 7, ko = col & 7;
                    h_t[tbase + (size_t)ktb * 8192 + (kb * 128 + row) * 8 + ko] = f2bf(hv);
                }
            }
        }
    }
}

// ---------------- stage B: outp = h @ Wd + bd (A reg-copied, B fp32-cvt staged) ----------------
__global__ __launch_bounds__(256, 2) void k_expert_down(
    const float* __restrict__ Wd, const float* __restrict__ bd,
    const ushort* __restrict__ h_t, const int* __restrict__ cnt,
    const int* __restrict__ abase, const int* __restrict__ tile,
    float* __restrict__ outp)
{
    int ti = tile[blockIdx.x];
    if (ti < 0) return;
    int e = ti >> 16, m0 = ti & 0xffff;
    int ne = cnt[e];
    int nt = blockIdx.y;                      // 0..7
    int n0 = nt * 128;
    int stile = (abase[e] >> 7) + (m0 >> 7);

    __shared__ __align__(16) ushort As8[8192];        // k-inner-8 image (16KB)
    __shared__ __align__(16) ushort Bd_s[8192];

    int tid = threadIdx.x;
    int lane = tid & 63, wave = tid >> 6;
    int wm = (wave & 1) * 64, wn = (wave >> 1) * 64;

    const uint4* hbase = (const uint4*)(h_t + (size_t)stile * 32 * 8192);  // 1024 uint4 per kt

    int skb = tid >> 5, sc4 = (tid & 31) * 4;
    const float* dp = Wd + (size_t)e * D_FF * D_MODEL + (size_t)(skb * 8) * D_MODEL + n0 + sc4;
    ushort* dds = Bd_s + (skb * 128 + sc4) * 8;

    f32x4 acc[4][4];
#pragma unroll
    for (int i = 0; i < 4; i++)
#pragma unroll
        for (int j = 0; j < 4; j++) acc[i][j] = (f32x4){0.f, 0.f, 0.f, 0.f};

    // preload kt=0
    uint4 va[4];
    float4 vd[8];
#pragma unroll
    for (int q = 0; q < 4; q++) va[q] = hbase[q * 256 + tid];
#pragma unroll
    for (int j = 0; j < 8; j++) vd[j] = *(const float4*)(dp + (size_t)j * D_MODEL);

    for (int kt = 0; kt < D_FF / 64; kt++) {
        __syncthreads();
        // A: linear 16KB copy from held regs
#pragma unroll
        for (int q = 0; q < 4; q++) ((uint4*)As8)[q * 256 + tid] = va[q];
        // B: cvt held regs -> k-inner-8 bf16
        u16x8 d0, d1, d2, d3;
#pragma unroll
        for (int j = 0; j < 8; j++) {
            d0[j] = f2bf(vd[j].x); d1[j] = f2bf(vd[j].y); d2[j] = f2bf(vd[j].z); d3[j] = f2bf(vd[j].w);
        }
        *(u16x8*)(dds + 0)  = d0; *(u16x8*)(dds + 8)  = d1;
        *(u16x8*)(dds + 16) = d2; *(u16x8*)(dds + 24) = d3;
        // prefetch next kt
        if (kt < D_FF / 64 - 1) {
            const uint4* hn = hbase + (kt + 1) * 1024;
            const float* dn = dp + (size_t)(kt + 1) * 64 * D_MODEL;
#pragma unroll
            for (int q = 0; q < 4; q++) va[q] = hn[q * 256 + tid];
#pragma unroll
            for (int j = 0; j < 8; j++) vd[j] = *(const float4*)(dn + (size_t)j * D_MODEL);
        }
        __syncthreads();
#pragma unroll
        for (int ks = 0; ks < 2; ks++) {
            bf16x8 af[4];
            int kb = ks * 4 + (lane >> 4);
            int arow_f = wm + (lane & 15);
#pragma unroll
            for (int sm = 0; sm < 4; sm++)
                af[sm] = *(const bf16x8*)&As8[(kb * 128 + arow_f + sm * 16) * 8];
#pragma unroll
            for (int sn = 0; sn < 4; sn++) {
                int ncol = wn + sn * 16 + (lane & 15);
                bf16x8 bdf = *(const bf16x8*)&Bd_s[(kb * 128 + ncol) * 8];
#pragma unroll
                for (int sm = 0; sm < 4; sm++)
                    acc[sm][sn] = __builtin_amdgcn_mfma_f32_16x16x32_bf16(af[sm], bdf, acc[sm][sn], 0, 0, 0);
            }
        }
    }
    int rbase = wm + ((lane >> 4) << 2);
    int cbase = wn + (lane & 15);
#pragma unroll
    for (int sm = 0; sm < 4; sm++) {
#pragma unroll
        for (int r = 0; r < 4; r++) {
            int pos = m0 + rbase + sm * 16 + r;
            if (pos < ne) {
                size_t ob = (size_t)(abase[e] + pos) * D_MODEL;
#pragma unroll
                for (int sn = 0; sn < 4; sn++) {
                    int col = n0 + cbase + sn * 16;
                    outp[ob + col] = acc[sm][sn][r] + bd[e * D_MODEL + col];
                }
            }
        }
    }
}

// ---------------- combine: y[t] = w0*outp[slot0] + w1*outp[slot1] ----------------
__global__ void k_combine(const float* __restrict__ outp, const int* __restrict__ slotpk,
                          const float* __restrict__ wtok, const int* __restrict__ abase,
                          float* __restrict__ y)
{
    int idx = blockIdx.x * 256 + threadIdx.x;   // 524288 float4s
    int t = idx >> 8, j = idx & 255;
    int sp0 = slotpk[t * 2 + 0], sp1 = slotpk[t * 2 + 1];
    float w0 = wtok[t * 2 + 0], w1 = wtok[t * 2 + 1];
    size_t s0 = (size_t)abase[sp0 >> 16] + (sp0 & 0xffff);
    size_t s1 = (size_t)abase[sp1 >> 16] + (sp1 & 0xffff);
    float4 a = ((const float4*)outp)[s0 * (D_MODEL / 4) + j];
    float4 b = ((const float4*)outp)[s1 * (D_MODEL / 4) + j];
    float4 o;
    o.x = w0 * a.x + w1 * b.x;
    o.y = w0 * a.y + w1 * b.y;
    o.z = w0 * a.z + w1 * b.z;
    o.w = w0 * a.w + w1 * b.w;
    ((float4*)y)[idx] = o;
}

extern "C" void kernel_launch(void* const* d_in, const int* in_sizes, int n_in,
                              void* d_out, int out_size, void* d_ws, size_t ws_size,
                              hipStream_t stream)
{
    const float* x  = (const float*)d_in[0];
    const float* gw = (const float*)d_in[1];
    const float* gb = (const float*)d_in[2];
    const float* Wg = (const float*)d_in[3];
    const float* bg = (const float*)d_in[4];
    const float* Wu = (const float*)d_in[5];
    const float* bu = (const float*)d_in[6];
    const float* Wd = (const float*)d_in[7];
    const float* bd = (const float*)d_in[8];
    float* y = (float*)d_out;
    float* loss_out = y + (size_t)T_TOK * D_MODEL;

    char* ws = (char*)d_ws;
    int*    cnt     = (int*)(ws + 0);             // 8 ints   [zeroed]  (own 128B line)
    float*  probsum = (float*)(ws + 128);         // 8 floats [zeroed]  (own 128B line)
    int*    abase   = (int*)(ws + 256);           // 8 ints (128-aligned bases)
    int*    tiletab = (int*)(ws + 320);           // MAXTILES ints
    int*    slotpk  = (int*)(ws + 512);           // 4096 ints
    float*  wtok    = (float*)(ws + 16896);       // 4096 floats
    int*    tok     = (int*)(ws + 33280);         // 8*2048 ints (ends 98816)
    ushort* xb      = (ushort*)(ws + 131072);     // 2M bf16 = 4 MB
    ushort* h_t     = (ushort*)(ws + 4325376);    // 40 tiles * 32 kt * 16KB = 20.97 MB
    float*  outp    = (float*)(ws + 25296896);    // 5120*1024 fp32 = 20.97 MB
    // total ws use: ~46.3 MB

    (void)hipMemsetAsync(d_ws, 0, 256, stream);
    k_router<<<dim3(64), dim3(256), 0, stream>>>(x, gw, gb, cnt, probsum, tok, slotpk, wtok, xb);
    k_base_loss<<<dim3(1), dim3(64), 0, stream>>>(cnt, probsum, abase, tiletab, loss_out);
    k_expert_gu<<<dim3(MAXTILES, 16), dim3(256), 0, stream>>>(Wg, Wu, bg, bu, xb, cnt, abase, tiletab, tok, h_t);
    k_expert_down<<<dim3(MAXTILES, 8), dim3(256), 0, stream>>>(Wd, bd, h_t, cnt, abase, tiletab, outp);
    k_combine<<<dim3(2048), dim3(256), 0, stream>>>(outp, slotpk, wtok, abase, y);
}

// Round 6
// 379.108 us; speedup vs baseline: 1.1960x; 1.1960x over previous
//
#include <hip/hip_runtime.h>
#include <hip/hip_bf16.h>

// MoE SwiGLU MLP, sparse top-2 path.
// T=2048 tokens, D_MODEL=1024, D_FF=2048, E=8 experts, K=2.
// R5 383.7us. R6 prep rewrite: null (2.2 TB/s invariant). R8 349.0us:
//     prep hidden under router (WgWu) + gu (Wd). gu 94us @ MfmaUtil 15.7%.
// R9 453us REGRESSION: direct-fp32 GEMM reads. FETCH 294MB/dispatch — the 4x
//     M-tile re-read of fp32 panels blew the L3 (134MB fp32 working set vs
//     67MB bf16). Lesson: prep = cache compression, not just format cvt.
// R10: revert to R8 pipeline + two fixes from R8 counters:
//     (a) gu As stride 88->72: LDS 55.3->51.2KB => 3 blocks/CU, all 640 gu
//         blocks co-resident (was 2 batches); __launch_bounds__(256,3).
//     (b) combine fused into down via atomicAdd(y, w*(acc+bd)) over zeroed y;
//         kills combine dispatch + outp round trip. Router emits wslot.
//     Predict gu 94->68-80us, total 349 -> ~295-315us.

#define D_MODEL 1024
#define D_FF    2048
#define N_EXP   8
#define T_TOK   2048
#define MAXTILES 40   // sum_e ceil(cnt_e/128) <= 32+7 < 40
#define ASTRIDE 72    // As leading dim: 16B-aligned, 2-way banks, 51.2KB total LDS

typedef __attribute__((ext_vector_type(8))) short bf16x8;
typedef __attribute__((ext_vector_type(8))) ushort u16x8;
typedef __attribute__((ext_vector_type(4))) float f32x4;

__device__ __forceinline__ ushort f2bf(float f) {
    union { float f; unsigned u; } c; c.f = f;
    unsigned u = c.u;
    return (ushort)((u + 0x7fffu + ((u >> 16) & 1u)) >> 16);  // RTNE
}

__device__ __forceinline__ void glds16(const void* g, void* l) {
    __builtin_amdgcn_global_load_lds(
        (const __attribute__((address_space(1))) unsigned int*)g,
        (__attribute__((address_space(3))) unsigned int*)l, 16, 0, 0);
}

// ---------------- prep helpers: fp32 -> bf16 tiled k-inner-8 (verified R6/R8) ----------------
// Output layout: tile t*8192 ushorts; within tile [(kb*128+ncol)*8+ko],
// k = kt*64 + kb*8 + ko. Wg/Wu: t = e*256 + nt*16 + kt. Wd: t = e*256 + nt*32 + kt.
__device__ __forceinline__ void prep_slab_gwu(
    int sp, int tid, const float* __restrict__ Wg, const float* __restrict__ Wu,
    ushort* __restrict__ Wgt, ushort* __restrict__ Wut, ushort* lds)
{
    int which = sp >> 10, s = sp & 1023;
    const float* src = which ? Wu : Wg;
    ushort* dst = which ? Wut : Wgt;
    int e = s >> 7, kt = (s >> 3) & 15, kb = s & 7;
    const float4* p = (const float4*)(src + (size_t)e * 1024 * 2048 + (size_t)(kt * 64 + kb * 8) * 2048);
#pragma unroll
    for (int i = 0; i < 16; i++) {
        float4 v = p[i * 256 + tid];
        ushort4 o;
        o.x = f2bf(v.x); o.y = f2bf(v.y); o.z = f2bf(v.z); o.w = f2bf(v.w);
        *(ushort4*)&lds[(i * 256 + tid) * 4] = o;
    }
    __syncthreads();
    u16x8 in[8];
#pragma unroll
    for (int ko = 0; ko < 8; ko++)
        in[ko] = *(const u16x8*)&lds[ko * 2048 + tid * 8];
    u16x8 out[8];
#pragma unroll
    for (int j = 0; j < 8; j++)
#pragma unroll
        for (int ko = 0; ko < 8; ko++)
            out[j][ko] = in[ko][j];
    __syncthreads();
    int swz = (tid & 7) << 4;
#pragma unroll
    for (int j = 0; j < 8; j++)
        *(u16x8*)((char*)lds + (((8 * tid + j) * 16) ^ swz)) = out[j];
    __syncthreads();
#pragma unroll
    for (int i = 0; i < 8; i++) {
        int c = i * 256 + tid;
        u16x8 v = *(const u16x8*)((char*)lds + ((c * 16) ^ (((c >> 3) & 7) << 4)));
        int R = c >> 7, q = c & 127;
        *(u16x8*)&dst[(size_t)(e * 256 + R * 16 + kt) * 8192 + kb * 1024 + q * 8] = v;
    }
}

__device__ __forceinline__ void prep_slab_wd(
    int s, int tid, const float* __restrict__ Wd, ushort* __restrict__ Wdt, ushort* lds)
{
    int e = s >> 7, kt = (s >> 2) & 31, kbp = s & 3;
    const float4* p = (const float4*)(Wd + (size_t)e * 2048 * 1024 + (size_t)(kt * 64 + kbp * 16) * 1024);
#pragma unroll
    for (int i = 0; i < 16; i++) {
        float4 v = p[i * 256 + tid];
        ushort4 o;
        o.x = f2bf(v.x); o.y = f2bf(v.y); o.z = f2bf(v.z); o.w = f2bf(v.w);
        *(ushort4*)&lds[(i * 256 + tid) * 4] = o;
    }
    __syncthreads();
    u16x8 in[8];
    int th = tid >> 7, tc = tid & 127;
#pragma unroll
    for (int ko = 0; ko < 8; ko++)
        in[ko] = *(const u16x8*)&lds[(th * 8 + ko) * 1024 + tc * 8];
    u16x8 out[8];
#pragma unroll
    for (int j = 0; j < 8; j++)
#pragma unroll
        for (int ko = 0; ko < 8; ko++)
            out[j][ko] = in[ko][j];
    __syncthreads();
    int swz = (tid & 7) << 4;
#pragma unroll
    for (int j = 0; j < 8; j++)
        *(u16x8*)((char*)lds + (((8 * tid + j) * 16) ^ swz)) = out[j];
    __syncthreads();
#pragma unroll
    for (int i = 0; i < 8; i++) {
        int c = i * 256 + tid;
        u16x8 v = *(const u16x8*)((char*)lds + ((c * 16) ^ (((c >> 3) & 7) << 4)));
        int R = c >> 7, q = c & 127;
        int kb2 = R >> 3, ntp = R & 7;
        *(u16x8*)&Wdt[(size_t)(e * 256 + ntp * 32 + kt) * 8192 + (kbp * 2 + kb2) * 1024 + q * 8] = v;
    }
}

// ---------------- launch 1: router (blocks 0..63) + Wg/Wu prep (64..2111) ----------------
union SM1 {
    float gws[N_EXP * D_MODEL];   // 32 KB router gate-weight cache
    ushort prep[16384];           // 32 KB prep scratch
};

__global__ __launch_bounds__(256) void k_router_prep(
    const float* __restrict__ x, const float* __restrict__ gw, const float* __restrict__ gb,
    int* cnt, float* probsum, int* tok, float* wslot,
    ushort* __restrict__ xb,
    const float* __restrict__ Wg, const float* __restrict__ Wu,
    ushort* __restrict__ Wgt, ushort* __restrict__ Wut)
{
    __shared__ __align__(16) SM1 sm;
    __shared__ float ps_s[N_EXP];
    __shared__ int   bc_s[N_EXP];
    __shared__ int   gb_s[N_EXP];
    __shared__ int   a_e[64];                // 32 tokens x 2 assignments
    __shared__ int   a_lp[64];
    __shared__ float a_w[64];

    int tid = threadIdx.x;
    int bid = blockIdx.x;

    if (bid >= 64) {                      // ---- prep role ----
        prep_slab_gwu(bid - 64, tid, Wg, Wu, Wgt, Wut, sm.prep);
        return;
    }

    // ---- router role ----
    float* gws = sm.gws;
    for (int i = tid; i < N_EXP * D_MODEL / 4; i += 256)
        ((float4*)gws)[i] = ((const float4*)gw)[i];
    if (tid < N_EXP) { ps_s[tid] = 0.f; bc_s[tid] = 0; }
    __syncthreads();

    int wave = tid >> 6, lane = tid & 63;

    for (int it = 0; it < 8; it++) {
        int tb = it * 4 + wave;                      // token-in-block
        int t = bid * 32 + tb;
        const float4* xr = (const float4*)(x + (size_t)t * D_MODEL);
        ushort* xbr = xb + (size_t)t * D_MODEL;

        float acc[N_EXP];
#pragma unroll
        for (int e = 0; e < N_EXP; e++) acc[e] = 0.f;
#pragma unroll
        for (int q = 0; q < 4; q++) {
            int idx = q * 64 + lane;                 // coalesced + uniform banking
            float4 xv = xr[idx];
            ushort4 xc;
            xc.x = f2bf(xv.x); xc.y = f2bf(xv.y); xc.z = f2bf(xv.z); xc.w = f2bf(xv.w);
            *(ushort4*)&xbr[idx * 4] = xc;
#pragma unroll
            for (int e = 0; e < N_EXP; e++) {
                float4 gv = ((const float4*)(gws + e * D_MODEL))[idx];
                acc[e] += xv.x * gv.x + xv.y * gv.y + xv.z * gv.z + xv.w * gv.w;
            }
        }
#pragma unroll
        for (int off = 32; off > 0; off >>= 1) {
#pragma unroll
            for (int e = 0; e < N_EXP; e++) acc[e] += __shfl_xor(acc[e], off, 64);
        }
        if (lane == 0) {
            float l[N_EXP], m = -1e30f;
#pragma unroll
            for (int e = 0; e < N_EXP; e++) { l[e] = acc[e] + gb[e]; m = fmaxf(m, l[e]); }
            float p[N_EXP], s = 0.f;
#pragma unroll
            for (int e = 0; e < N_EXP; e++) { p[e] = expf(l[e] - m); s += p[e]; }
            float inv = 1.f / s;
#pragma unroll
            for (int e = 0; e < N_EXP; e++) { p[e] *= inv; atomicAdd(&ps_s[e], p[e]); }
            // top-2, lowest index wins ties (matches lax.top_k)
            int i0 = 0; float v0 = p[0];
#pragma unroll
            for (int e = 1; e < N_EXP; e++) if (p[e] > v0) { v0 = p[e]; i0 = e; }
            int i1 = -1; float v1 = -1.f;
#pragma unroll
            for (int e = 0; e < N_EXP; e++) if (e != i0 && p[e] > v1) { v1 = p[e]; i1 = e; }
            float winv = 1.f / (v0 + v1);
            int lp0 = atomicAdd(&bc_s[i0], 1);
            int lp1 = atomicAdd(&bc_s[i1], 1);
            a_e[tb * 2 + 0] = i0; a_lp[tb * 2 + 0] = lp0; a_w[tb * 2 + 0] = v0 * winv;
            a_e[tb * 2 + 1] = i1; a_lp[tb * 2 + 1] = lp1; a_w[tb * 2 + 1] = v1 * winv;
        }
    }
    __syncthreads();
    if (tid < N_EXP) {
        gb_s[tid] = atomicAdd(&cnt[tid], bc_s[tid]);
        atomicAdd(&probsum[tid], ps_s[tid]);
    }
    __syncthreads();
    if (tid < 64) {
        int tb = tid >> 1;
        int t = bid * 32 + tb;
        int e = a_e[tid];
        int slot = gb_s[e] + a_lp[tid];
        tok[e * T_TOK + slot] = t;
        wslot[e * T_TOK + slot] = a_w[tid];
    }
}

// ---------------- 128-aligned expert bases + tile table + balance loss ----------------
__global__ void k_base_loss(const int* __restrict__ cnt, const float* __restrict__ probsum,
                            int* abase, int* tile, float* loss_out)
{
    if (threadIdx.x == 0 && blockIdx.x == 0) {
        int b = 0, nt = 0;
        float loss = 0.f;
        for (int e = 0; e < N_EXP; e++) {
            abase[e] = b;
            for (int m0 = 0; m0 < cnt[e]; m0 += 128)
                tile[nt++] = (e << 16) | m0;
            b += ((cnt[e] + 127) >> 7) * 128;           // capacity-aligned
            float mean = probsum[e] * (1.0f / T_TOK);
            loss += 0.125f * (logf(0.125f) - logf(mean + 1e-9f));
        }
        for (; nt < MAXTILES; nt++) tile[nt] = -1;
        *loss_out = loss;
    }
}

// ---------------- launch 3: stage A gu-GEMM (blocks 0..639) + Wd prep (640..1663) ----------------
struct SM_GU { ushort As[128 * ASTRIDE]; ushort Bg[8192]; ushort Bu[8192]; };  // 51.2 KB
union SM3 {
    SM_GU g;
    ushort prep[16384]; // 32 KB prep scratch
};

__global__ __launch_bounds__(256, 3) void k_gu_prepwd(
    const ushort* __restrict__ Wgt, const ushort* __restrict__ Wut,
    const float* __restrict__ bg, const float* __restrict__ bu,
    const ushort* __restrict__ xb, const int* __restrict__ cnt,
    const int* __restrict__ abase, const int* __restrict__ tile,
    const int* __restrict__ tok, ushort* __restrict__ h_t,
    const float* __restrict__ Wd, ushort* __restrict__ Wdt)
{
    __shared__ __align__(16) SM3 sm;

    int bid = blockIdx.x;
    int tid = threadIdx.x;

    if (bid >= MAXTILES * 16) {           // ---- prep-Wd role ----
        prep_slab_wd(bid - MAXTILES * 16, tid, Wd, Wdt, sm.prep);
        return;
    }

    // ---- gu GEMM role ----
    int ti = tile[bid % MAXTILES];
    if (ti < 0) return;                       // contiguous tail only
    int e = ti >> 16, m0 = ti & 0xffff;
    int ne = cnt[e];
    int nt = bid / MAXTILES;                  // 0..15
    int n0 = nt * 128;
    int stile = (abase[e] >> 7) + (m0 >> 7);  // global aligned slot-tile

    ushort* As = sm.g.As;
    ushort* Bg_s = sm.g.Bg;
    ushort* Bu_s = sm.g.Bu;

    int lane = tid & 63, wave = tid >> 6;
    int wm = (wave & 1) * 64, wn = (wave >> 1) * 64;

    // A staging: thread -> (row, k-half)
    int arow = tid >> 1;
    int akh = (tid & 1) * 32;
    int atok = tok[e * T_TOK + min(m0 + arow, ne - 1)];
    const ushort* xrow = xb + (size_t)atok * D_MODEL;

    // B tile bases (16KB per kt)
    const char* gbase = (const char*)(Wgt + (size_t)(e * 16 + nt) * 16 * 8192);
    const char* ubase = (const char*)(Wut + (size_t)(e * 16 + nt) * 16 * 8192);
    int goff = tid * 16;                      // per-lane global byte offset in tile
    int loff = (tid >> 6) * 1024;             // wave-uniform LDS byte offset

    f32x4 accg[4][4], accu[4][4];
#pragma unroll
    for (int i = 0; i < 4; i++)
#pragma unroll
        for (int j = 0; j < 4; j++) {
            accg[i][j] = (f32x4){0.f, 0.f, 0.f, 0.f};
            accu[i][j] = (f32x4){0.f, 0.f, 0.f, 0.f};
        }

    for (int kt = 0; kt < D_MODEL / 64; kt++) {
        __syncthreads();
        // A tile: bf16 gather copy, 16B chunks
#pragma unroll
        for (int q = 0; q < 4; q++)
            *(uint4*)&As[arow * ASTRIDE + akh + q * 8] = *(const uint4*)&xrow[kt * 64 + akh + q * 8];
        // B tiles: direct-to-LDS block copy (16KB each)
        const char* gsrc = gbase + kt * 16384;
        const char* usrc = ubase + kt * 16384;
#pragma unroll
        for (int q = 0; q < 4; q++) {
            glds16(gsrc + q * 4096 + goff, (char*)Bg_s + q * 4096 + loff);
            glds16(usrc + q * 4096 + goff, (char*)Bu_s + q * 4096 + loff);
        }
        __syncthreads();
        // compute
#pragma unroll
        for (int ks = 0; ks < 2; ks++) {
            bf16x8 af[4];
            int arow_f = wm + (lane & 15);
            int akb = ks * 32 + (lane >> 4) * 8;
#pragma unroll
            for (int sm_ = 0; sm_ < 4; sm_++)
                af[sm_] = *(const bf16x8*)&As[(arow_f + sm_ * 16) * ASTRIDE + akb];
            int bkb = ks * 4 + (lane >> 4);
#pragma unroll
            for (int sn = 0; sn < 4; sn++) {
                int ncol = wn + sn * 16 + (lane & 15);
                bf16x8 bgf = *(const bf16x8*)&Bg_s[(bkb * 128 + ncol) * 8];
                bf16x8 buf = *(const bf16x8*)&Bu_s[(bkb * 128 + ncol) * 8];
#pragma unroll
                for (int sm_ = 0; sm_ < 4; sm_++) {
                    accg[sm_][sn] = __builtin_amdgcn_mfma_f32_16x16x32_bf16(af[sm_], bgf, accg[sm_][sn], 0, 0, 0);
                    accu[sm_][sn] = __builtin_amdgcn_mfma_f32_16x16x32_bf16(af[sm_], buf, accu[sm_][sn], 0, 0, 0);
                }
            }
        }
    }
    // epilogue: silu(g)*u -> h_t (bf16, tiled k-inner-8 for stage B's A-operand)
    int rbase = wm + ((lane >> 4) << 2);
    int cbase = wn + (lane & 15);
    size_t tbase = (size_t)stile * 32 * 8192;
#pragma unroll
    for (int sm_ = 0; sm_ < 4; sm_++) {
#pragma unroll
        for (int r = 0; r < 4; r++) {
            int pos = m0 + rbase + sm_ * 16 + r;
            if (pos < ne) {
                int row = pos & 127;
#pragma unroll
                for (int sn = 0; sn < 4; sn++) {
                    int col = n0 + cbase + sn * 16;
                    float g = accg[sm_][sn][r] + bg[e * D_FF + col];
                    float u = accu[sm_][sn][r] + bu[e * D_FF + col];
                    float hv = (g / (1.f + expf(-g))) * u;
                    int ktb = col >> 6, kb = (col >> 3) & 7, ko = col & 7;
                    h_t[tbase + (size_t)ktb * 8192 + (kb * 128 + row) * 8 + ko] = f2bf(hv);
                }
            }
        }
    }
}

// ---------------- stage B + combine: y[t] += w * (h @ Wd + bd) ----------------
__global__ __launch_bounds__(256, 2) void k_down_combine(
    const ushort* __restrict__ Wdt, const float* __restrict__ bd,
    const ushort* __restrict__ h_t, const int* __restrict__ cnt,
    const int* __restrict__ abase, const int* __restrict__ tile,
    const int* __restrict__ tok, const float* __restrict__ wslot,
    float* __restrict__ y)
{
    int ti = tile[blockIdx.x];
    if (ti < 0) return;
    int e = ti >> 16, m0 = ti & 0xffff;
    int ne = cnt[e];
    int nt = blockIdx.y;                      // 0..7
    int n0 = nt * 128;
    int stile = (abase[e] >> 7) + (m0 >> 7);

    __shared__ __align__(16) ushort As8[8192];        // k-inner-8 image (16KB)
    __shared__ __align__(16) ushort Bd_s[8192];

    int tid = threadIdx.x;
    int lane = tid & 63, wave = tid >> 6;
    int wm = (wave & 1) * 64, wn = (wave >> 1) * 64;

    const char* hbase = (const char*)(h_t + (size_t)stile * 32 * 8192);
    const char* dbase = (const char*)(Wdt + (size_t)(e * 8 + nt) * 32 * 8192);
    int goff = tid * 16;
    int loff = (tid >> 6) * 1024;

    f32x4 acc[4][4];
#pragma unroll
    for (int i = 0; i < 4; i++)
#pragma unroll
        for (int j = 0; j < 4; j++) acc[i][j] = (f32x4){0.f, 0.f, 0.f, 0.f};

    for (int kt = 0; kt < D_FF / 64; kt++) {
        __syncthreads();
        const char* asrc = hbase + kt * 16384;
        const char* bsrc = dbase + kt * 16384;
#pragma unroll
        for (int q = 0; q < 4; q++) {
            glds16(asrc + q * 4096 + goff, (char*)As8 + q * 4096 + loff);
            glds16(bsrc + q * 4096 + goff, (char*)Bd_s + q * 4096 + loff);
        }
        __syncthreads();
#pragma unroll
        for (int ks = 0; ks < 2; ks++) {
            bf16x8 af[4];
            int kb = ks * 4 + (lane >> 4);
            int arow_f = wm + (lane & 15);
#pragma unroll
            for (int sm_ = 0; sm_ < 4; sm_++)
                af[sm_] = *(const bf16x8*)&As8[(kb * 128 + arow_f + sm_ * 16) * 8];
#pragma unroll
            for (int sn = 0; sn < 4; sn++) {
                int ncol = wn + sn * 16 + (lane & 15);
                bf16x8 bdf = *(const bf16x8*)&Bd_s[(kb * 128 + ncol) * 8];
#pragma unroll
                for (int sm_ = 0; sm_ < 4; sm_++)
                    acc[sm_][sn] = __builtin_amdgcn_mfma_f32_16x16x32_bf16(af[sm_], bdf, acc[sm_][sn], 0, 0, 0);
            }
        }
    }
    // fused combine epilogue: y[t] += w * (acc + bd)
    int rbase = wm + ((lane >> 4) << 2);
    int cbase = wn + (lane & 15);
#pragma unroll
    for (int sm_ = 0; sm_ < 4; sm_++) {
#pragma unroll
        for (int r = 0; r < 4; r++) {
            int pos = m0 + rbase + sm_ * 16 + r;
            if (pos < ne) {
                int t = tok[e * T_TOK + pos];
                float w = wslot[e * T_TOK + pos];
                float* yrow = y + (size_t)t * D_MODEL;
#pragma unroll
                for (int sn = 0; sn < 4; sn++) {
                    int col = n0 + cbase + sn * 16;
                    atomicAdd(&yrow[col], w * (acc[sm_][sn][r] + bd[e * D_MODEL + col]));
                }
            }
        }
    }
}

extern "C" void kernel_launch(void* const* d_in, const int* in_sizes, int n_in,
                              void* d_out, int out_size, void* d_ws, size_t ws_size,
                              hipStream_t stream)
{
    const float* x  = (const float*)d_in[0];
    const float* gw = (const float*)d_in[1];
    const float* gb = (const float*)d_in[2];
    const float* Wg = (const float*)d_in[3];
    const float* bg = (const float*)d_in[4];
    const float* Wu = (const float*)d_in[5];
    const float* bu = (const float*)d_in[6];
    const float* Wd = (const float*)d_in[7];
    const float* bd = (const float*)d_in[8];
    float* y = (float*)d_out;
    float* loss_out = y + (size_t)T_TOK * D_MODEL;

    char* ws = (char*)d_ws;
    int*    cnt     = (int*)(ws + 0);             // 8 ints   [zeroed]  (own 128B line)
    float*  probsum = (float*)(ws + 128);         // 8 floats [zeroed]
    int*    abase   = (int*)(ws + 256);           // 8 ints
    int*    tiletab = (int*)(ws + 320);           // MAXTILES ints
    float*  wslot   = (float*)(ws + 1024);        // 8*2048 floats (64 KB) -> ends 66560
    int*    tok     = (int*)(ws + 66560);         // 8*2048 ints  (64 KB) -> ends 132096
    ushort* xb      = (ushort*)(ws + 135168);     // 2M bf16 = 4 MB -> ends 4329472
    ushort* Wgt     = (ushort*)(ws + 4329472);    // 33.55 MB tiled bf16
    ushort* Wut     = (ushort*)(ws + 37883904);   // 33.55 MB
    ushort* Wdt     = (ushort*)(ws + 71438336);   // 33.55 MB
    ushort* h_t     = (ushort*)(ws + 104992768);  // 40 tiles * 32 kt * 16KB = 20.97 MB
    // total ws use: ~126 MB

    (void)hipMemsetAsync(d_ws, 0, 256, stream);
    (void)hipMemsetAsync(y, 0, (size_t)T_TOK * D_MODEL * sizeof(float), stream);
    // launch 1: router (64 blocks) overlapped with Wg/Wu prep (2048 blocks)
    k_router_prep<<<dim3(64 + 2048), dim3(256), 0, stream>>>(
        x, gw, gb, cnt, probsum, tok, wslot, xb, Wg, Wu, Wgt, Wut);
    k_base_loss<<<dim3(1), dim3(64), 0, stream>>>(cnt, probsum, abase, tiletab, loss_out);
    // launch 3: gu GEMM (640 blocks) overlapped with Wd prep (1024 blocks)
    k_gu_prepwd<<<dim3(MAXTILES * 16 + 1024), dim3(256), 0, stream>>>(
        Wgt, Wut, bg, bu, xb, cnt, abase, tiletab, tok, h_t, Wd, Wdt);
    // launch 4: down-GEMM with fused weighted-atomic combine
    k_down_combine<<<dim3(MAXTILES, 8), dim3(256), 0, stream>>>(
        Wdt, bd, h_t, cnt, abase, tiletab, tok, wslot, y);
}